// Round 13
// baseline (514.507 us; speedup 1.0000x reference)
//
#include <hip/hip_runtime.h>

// ---------------------------------------------------------------------------
// LSH self-attention (Reformer). B=2,S=4096,H=16,D=64,NH=2,NB=128,CHUNK=64,
// N_BEFORE=1. Inputs fp32, output fp32.
// Precision-critical path (qk projection + hash einsum feeding argmax) is
// fp32 with sequential ascending-k FMA chains (matches np/BLAS order).
// Attention on bf16 MFMA (smooth path). v projection: bf16x2-split MFMA GEMM.
// Sort: ballot stable multisplit.
// gemm_qk history: R1 conflict fix 238->225; R4 8x8/128x128: 224 = source
//   ceiling for sequential-k fp32 (R5/R6/R7 all regressed).
// R8 (verified): split folded into qk dispatch as trailing streamer blocks —
//   223us fused (split absorbed via block backfill), total 513.3.
// R11 (neutral): qkb bf16 copy + ssqo row-sumsq emitted from qk epilogue;
//   attn stages via straight copies. attn got ~20us faster BUT the 16KB ssq
//   LDS buffer pushed LDS 16.9->33.3KB, halving split-block backfill ->
//   qk dispatch 223->244. Net 0.
// R12: alias ssq onto the dead As/Bs LDS (16896B >= 16384B needed; all
//   As/Bs reads complete before the K-loop's final barrier). LDS back to
//   16896 -> backfill restored, attn savings kept. Arithmetic unchanged.
// ---------------------------------------------------------------------------

typedef __attribute__((ext_vector_type(4))) float          f32x4;
typedef __attribute__((ext_vector_type(4))) unsigned short u16x4;
typedef __attribute__((ext_vector_type(8))) unsigned short u16x8;
typedef __attribute__((ext_vector_type(8))) __bf16         bf16x8;

__device__ __forceinline__ float bf2f(unsigned short u) {
    unsigned int x = ((unsigned int)u) << 16;
    return __builtin_bit_cast(float, x);
}
__device__ __forceinline__ unsigned short f2bf(float f) {
    unsigned int x = __builtin_bit_cast(unsigned int, f);
    x += 0x7FFFu + ((x >> 16) & 1u);
    return (unsigned short)(x >> 16);
}

// async global->LDS, 16B per lane, wave-uniform LDS base (HW adds lane*16).
__device__ __forceinline__ void gll16(const unsigned short* g, unsigned short* l) {
    __builtin_amdgcn_global_load_lds(
        (__attribute__((address_space(1))) void*)(g),
        (__attribute__((address_space(3))) void*)(l),
        16, 0, 0);
}

// ---------------------------------------------------------------------------
// Kernel 1a: qk projection (R4-exact core) + hidden/wv hi-lo split as
// trailing blocks. Blocks 0..511: qk 128x128 tile, 8x8/thread, fp32
// sequential ascending-k FMA — DO NOT change accumulation order (argmax).
// Epilogue emits bf16 qk copy (qkb) + per-row sumsq (ssqo); the sumsq
// scratch ALIASES the dead As/Bs LDS (keeps LDS at 16896B for backfill).
// Blocks 512..9727: split streamer (no LDS use, no barriers).
// ---------------------------------------------------------------------------
__global__ __launch_bounds__(256)
void gemm_qk_split(const float* __restrict__ hidden,
                   const float* __restrict__ wqk,
                   float* __restrict__ qk_out,
                   unsigned short* __restrict__ qkb,
                   float* __restrict__ ssqo,
                   const float* __restrict__ wv,
                   unsigned short* __restrict__ hH, unsigned short* __restrict__ hL,
                   unsigned short* __restrict__ wH, unsigned short* __restrict__ wL)
{
    __shared__ __attribute__((aligned(16))) char qsmem[16896];  // As|Bs, later ssq
    float (*As)[132] = (float(*)[132])qsmem;            //  8448 B
    float (*Bs)[132] = (float(*)[132])(qsmem + 8448);   //  8448 B
    const int tid = threadIdx.x;

    if (blockIdx.x >= 512) {
        // ---- split path: hidden (2097152 vec4) then wv (262144 vec4) ----
        const int idx = (blockIdx.x - 512) * 256 + tid;    // < 2359296
        const bool isw = idx >= 2097152;
        const float* src = isw ? wv : hidden;
        unsigned short* dh = isw ? wH : hH;
        unsigned short* dl = isw ? wL : hL;
        const int v = isw ? (idx - 2097152) : idx;
        const f32x4 x = *((const f32x4*)src + v);
        u16x4 h, l;
#pragma unroll
        for (int j = 0; j < 4; ++j) {
            const unsigned short hs = f2bf(x[j]);
            h[j] = hs;
            l[j] = f2bf(x[j] - bf2f(hs));   // x - bf2f(hi) exact (Sterbenz)
        }
        *((u16x4*)dh + v) = h;
        *((u16x4*)dl + v) = l;
        return;
    }

    // ---- qk path (R4-exact main loop) ----
    const int bm  = blockIdx.x & 63;    // 0..63
    const int bn  = blockIdx.x >> 6;    // 0..7

    const float* Asrc = hidden + (size_t)bm * 128 * 1024;
    const float* Bsrc = wqk + (size_t)bn * 128 * 1024;

    const int mlo = (tid & 15) * 4;     // A-read base (16B-stride, 2-way free)
    const int nlo = (tid >> 4) * 4;     // B-read base (broadcast groups)

    float acc[8][8];
#pragma unroll
    for (int r = 0; r < 8; ++r)
#pragma unroll
        for (int c = 0; c < 8; ++c) acc[r][c] = 0.f;

    int srow[2], skof[2];
#pragma unroll
    for (int i = 0; i < 2; ++i) {
        const int c = i * 256 + tid;
        srow[i] = c >> 2;
        skof[i] = (c & 3) * 4;
    }

    f32x4 apre[2], bpre[2];
#pragma unroll
    for (int i = 0; i < 2; ++i) {
        apre[i] = *(const f32x4*)(Asrc + (size_t)srow[i] * 1024 + skof[i]);
        bpre[i] = *(const f32x4*)(Bsrc + (size_t)srow[i] * 1024 + skof[i]);
    }

    for (int ks = 0; ks < 64; ++ks) {   // K = 64 tiles * 16, ascending
#pragma unroll
        for (int i = 0; i < 2; ++i)
#pragma unroll
            for (int j = 0; j < 4; ++j) {
                As[skof[i] + j][srow[i]] = apre[i][j];
                Bs[skof[i] + j][srow[i]] = bpre[i][j];
            }
        __syncthreads();
        if (ks < 63) {
            const int k0 = (ks + 1) * 16;
#pragma unroll
            for (int i = 0; i < 2; ++i) {
                apre[i] = *(const f32x4*)(Asrc + (size_t)srow[i] * 1024 + k0 + skof[i]);
                bpre[i] = *(const f32x4*)(Bsrc + (size_t)srow[i] * 1024 + k0 + skof[i]);
            }
        }
#pragma unroll
        for (int k = 0; k < 16; ++k) {
            f32x4 a0 = *(const f32x4*)&As[k][mlo];
            f32x4 a1 = *(const f32x4*)&As[k][64 + mlo];
            f32x4 b0 = *(const f32x4*)&Bs[k][nlo];
            f32x4 b1 = *(const f32x4*)&Bs[k][64 + nlo];
#pragma unroll
            for (int c = 0; c < 4; ++c) {
#pragma unroll
                for (int r = 0; r < 4; ++r) {
                    acc[r][c]         = __builtin_fmaf(a0[r], b0[c], acc[r][c]);
                    acc[r][c + 4]     = __builtin_fmaf(a0[r], b1[c], acc[r][c + 4]);
                    acc[r + 4][c]     = __builtin_fmaf(a1[r], b0[c], acc[r + 4][c]);
                    acc[r + 4][c + 4] = __builtin_fmaf(a1[r], b1[c], acc[r + 4][c + 4]);
                }
            }
        }
        __syncthreads();
    }

    // ---- epilogue. As/Bs dead past the final barrier: reuse as ssq ----
    float* ssq = (float*)qsmem;          // [16][256] partials, 16384 B

#pragma unroll
    for (int r = 0; r < 8; ++r) {
        const int mm = (r < 4) ? (mlo + r) : (64 + mlo + (r - 4));
#pragma unroll
        for (int g = 0; g < 2; ++g) {
            float p = acc[r][g * 4 + 0] * acc[r][g * 4 + 0];
            p = __builtin_fmaf(acc[r][g * 4 + 1], acc[r][g * 4 + 1], p);
            p = __builtin_fmaf(acc[r][g * 4 + 2], acc[r][g * 4 + 2], p);
            p = __builtin_fmaf(acc[r][g * 4 + 3], acc[r][g * 4 + 3], p);
            ssq[(tid >> 4) * 256 + mm * 2 + g] = p;
        }
    }

#pragma unroll
    for (int r = 0; r < 8; ++r) {
        const int mm = (r < 4) ? (mlo + r) : (64 + mlo + (r - 4));
        const int m  = bm * 128 + mm;
        const int bb = m >> 12, s = m & 4095;
#pragma unroll
        for (int g = 0; g < 2; ++g) {
            const int n  = bn * 128 + (g ? (64 + nlo) : nlo);   // 4-aligned
            const int hh = n >> 6, d = n & 63;
            f32x4 v;
            u16x4 hb;
#pragma unroll
            for (int c = 0; c < 4; ++c) { v[c] = acc[r][g * 4 + c]; hb[c] = f2bf(v[c]); }
            const size_t ob = (((size_t)(bb * 16 + hh)) * 4096 + s) * 64 + d;
            *(f32x4*)&qk_out[ob] = v;
            *(u16x4*)&qkb[ob]    = hb;
        }
    }

    __syncthreads();
    {
        // 256 threads: one (row, g) each. Reads conflict-free (consecutive).
        const int rw = tid >> 1, g = tid & 1;
        float tot = 0.f;
#pragma unroll
        for (int i = 0; i < 16; ++i) tot += ssq[i * 256 + tid];
        const int m  = bm * 128 + rw;
        const int bb = m >> 12, s = m & 4095;
        const int hh = bn * 2 + g;
        ssqo[((size_t)(bb * 16 + hh)) * 4096 + s] = tot;
    }
}

// ---------------------------------------------------------------------------
// Kernel 1b: v projection as bf16x2-split MFMA GEMM.
// C[m][n] = sum_k (Ah+Al)[m][k] * (Bh+Bl)[n][k], dropping Al*Bl (~2^-18 rel).
// BM=128, BN=128, BK=32, 4 waves, each wave owns a 64x64 quadrant.
// ---------------------------------------------------------------------------
__global__ __launch_bounds__(256)
void gemm_v(const unsigned short* __restrict__ hH,
            const unsigned short* __restrict__ hL,
            const unsigned short* __restrict__ wH,
            const unsigned short* __restrict__ wL,
            unsigned short* __restrict__ v_out)
{
    __shared__ __attribute__((aligned(16))) unsigned short Ah[128 * 32];
    __shared__ __attribute__((aligned(16))) unsigned short Al[128 * 32];
    __shared__ __attribute__((aligned(16))) unsigned short Bh[128 * 32];
    __shared__ __attribute__((aligned(16))) unsigned short Bl[128 * 32];

    const int tid  = threadIdx.x;
    const int bm   = blockIdx.x;          // 0..63  (M = 8192)
    const int bn   = blockIdx.y;          // 0..7   (N = 1024)
    const int w    = tid >> 6;
    const int lane = tid & 63;
    const int l16  = lane & 15;
    const int quad = lane >> 4;
    const int m0   = (w >> 1) * 64;
    const int n0   = (w & 1) * 64;

    const int c0 = w * 2;
    const int r0 = c0 * 16 + (lane >> 2);   // tile row for chunk c0
    const int r1 = r0 + 16;                 // tile row for chunk c0+1
    const int kf = (lane & 3) * 8;          // k offset in shorts

    const size_t abase = (size_t)bm * 128 * 1024;   // shorts
    const size_t bbase = (size_t)bn * 128 * 1024;

    f32x4 acc[4][4];
#pragma unroll
    for (int i = 0; i < 4; ++i)
#pragma unroll
        for (int j = 0; j < 4; ++j) acc[i][j] = f32x4{0.f, 0.f, 0.f, 0.f};

    for (int ks = 0; ks < 32; ++ks) {
        const int kb = ks * 32 + kf;
        gll16(hH + abase + (size_t)r0 * 1024 + kb, Ah + (size_t)c0 * 512);
        gll16(hH + abase + (size_t)r1 * 1024 + kb, Ah + (size_t)(c0 + 1) * 512);
        gll16(hL + abase + (size_t)r0 * 1024 + kb, Al + (size_t)c0 * 512);
        gll16(hL + abase + (size_t)r1 * 1024 + kb, Al + (size_t)(c0 + 1) * 512);
        gll16(wH + bbase + (size_t)r0 * 1024 + kb, Bh + (size_t)c0 * 512);
        gll16(wH + bbase + (size_t)r1 * 1024 + kb, Bh + (size_t)(c0 + 1) * 512);
        gll16(wL + bbase + (size_t)r0 * 1024 + kb, Bl + (size_t)c0 * 512);
        gll16(wL + bbase + (size_t)r1 * 1024 + kb, Bl + (size_t)(c0 + 1) * 512);
        __syncthreads();   // drains vmcnt (global_load_lds) + barrier

        bf16x8 ahf[4], alf[4], bhf[4], blf[4];
#pragma unroll
        for (int i = 0; i < 4; ++i) {
            ahf[i] = *(const bf16x8*)&Ah[(m0 + i * 16 + l16) * 32 + quad * 8];
            alf[i] = *(const bf16x8*)&Al[(m0 + i * 16 + l16) * 32 + quad * 8];
        }
#pragma unroll
        for (int j = 0; j < 4; ++j) {
            bhf[j] = *(const bf16x8*)&Bh[(n0 + j * 16 + l16) * 32 + quad * 8];
            blf[j] = *(const bf16x8*)&Bl[(n0 + j * 16 + l16) * 32 + quad * 8];
        }
#pragma unroll
        for (int i = 0; i < 4; ++i)
#pragma unroll
            for (int j = 0; j < 4; ++j) {
                acc[i][j] = __builtin_amdgcn_mfma_f32_16x16x32_bf16(ahf[i], bhf[j], acc[i][j], 0, 0, 0);
                acc[i][j] = __builtin_amdgcn_mfma_f32_16x16x32_bf16(alf[i], bhf[j], acc[i][j], 0, 0, 0);
                acc[i][j] = __builtin_amdgcn_mfma_f32_16x16x32_bf16(ahf[i], blf[j], acc[i][j], 0, 0, 0);
            }
        __syncthreads();   // tile fully consumed before next stage overwrites
    }

    // C/D layout [m89]: col = lane&15 (n index), row = quad*4 + reg (m index)
#pragma unroll
    for (int i = 0; i < 4; ++i) {
#pragma unroll
        for (int r = 0; r < 4; ++r) {
            const int m  = bm * 128 + m0 + i * 16 + quad * 4 + r;
            const int bb = m >> 12, s = m & 4095;
#pragma unroll
            for (int j = 0; j < 4; ++j) {
                const int n  = bn * 128 + n0 + j * 16 + l16;
                const int hh = n >> 6, d = n & 63;
                v_out[(((size_t)(bb * 16 + hh)) * 4096 + s) * 64 + d] = f2bf(acc[i][j][r]);
            }
        }
    }
}

// ---------------------------------------------------------------------------
// Kernel 2: hashing. Sequential ascending-d fp32 FMA; argmax over
// concat(rot,-rot), first-occurrence ties. One wave per row-group.
// Reads fp32 qk (exact — buckets must not change).
// ---------------------------------------------------------------------------
__global__ __launch_bounds__(256)
void hash_kernel(const float* __restrict__ qk,
                 const float* __restrict__ rotf,
                 int* __restrict__ buckets)
{
    __shared__ float rot[8192];       // [d][n*64+r]
    __shared__ float rows[64 * 64];
    const int tid = threadIdx.x;
    for (int i = tid; i < 8192; i += 256) rot[i] = rotf[i];
    const int rbase = blockIdx.x * 64;
    {
        const f32x4* src = (const f32x4*)(qk + (size_t)rbase * 64);
        f32x4* dst = (f32x4*)rows;
#pragma unroll
        for (int i = 0; i < 4; ++i) dst[tid + i * 256] = src[tid + i * 256];
    }
    __syncthreads();
    const int w = tid >> 6, lane = tid & 63;
    for (int rr = 0; rr < 16; ++rr) {
        const int row = w * 16 + rr;
        float a0 = 0.f, a1 = 0.f;
#pragma unroll
        for (int dg = 0; dg < 16; ++dg) {
            f32x4 qb = *(const f32x4*)&rows[row * 64 + dg * 4];
#pragma unroll
            for (int j = 0; j < 4; ++j) {
                const int d = dg * 4 + j;
                a0 = __builtin_fmaf(qb[j], rot[d * 128 + lane],      a0);
                a1 = __builtin_fmaf(qb[j], rot[d * 128 + 64 + lane], a1);
            }
        }
        float v0, v1; int i0, i1;
        if (a0 >= -a0) { v0 = a0;  i0 = lane; } else { v0 = -a0; i0 = 64 + lane; }
        if (a1 >= -a1) { v1 = a1;  i1 = lane; } else { v1 = -a1; i1 = 64 + lane; }
#pragma unroll
        for (int m = 1; m < 64; m <<= 1) {
            float ov = __shfl_xor(v0, m); int oi = __shfl_xor(i0, m);
            if (ov > v0 || (ov == v0 && oi < i0)) { v0 = ov; i0 = oi; }
            ov = __shfl_xor(v1, m); oi = __shfl_xor(i1, m);
            if (ov > v1 || (ov == v1 && oi < i1)) { v1 = ov; i1 = oi; }
        }
        if (lane == 0) {
            const int g = rbase + row;
            const int bh = g >> 12, s = g & 4095;
            buckets[(size_t)bh * 8192 + s]        = i0;          // hash 0
            buckets[(size_t)bh * 8192 + 4096 + s] = i1 + 128;    // hash 1
        }
    }
}

// ---------------------------------------------------------------------------
// Kernel 3: stable counting sort per (b,h) by (bucket, position).
// Ballot-based multisplit (round-8 verified).
// ---------------------------------------------------------------------------
__global__ __launch_bounds__(256)
void sort_kernel(const int* __restrict__ buckets, int* __restrict__ sorted)
{
    __shared__ unsigned char  lb[8192];
    __shared__ unsigned short sl[8192];
    __shared__ int cnt[256];
    __shared__ int base[256];
    __shared__ unsigned short whist[4][256];
    const int tid  = threadIdx.x;
    const int bh   = blockIdx.x;
    const int lane = tid & 63;
    const int w    = tid >> 6;

    cnt[tid] = 0;
    for (int i = tid; i < 8192; i += 256)
        lb[i] = (unsigned char)buckets[(size_t)bh * 8192 + i];
    __syncthreads();
    for (int i = tid; i < 8192; i += 256) atomicAdd(&cnt[lb[i]], 1);
    __syncthreads();

    base[tid] = cnt[tid];
    __syncthreads();
#pragma unroll
    for (int off = 1; off < 256; off <<= 1) {
        int t = (tid >= off) ? base[tid - off] : 0;
        __syncthreads();
        base[tid] += t;
        __syncthreads();
    }
    {
        int ex = base[tid] - cnt[tid];
        __syncthreads();
        base[tid] = ex;
        __syncthreads();
    }

    for (int c = 0; c < 32; ++c) {
        const int i = c * 256 + tid;
        const int b = lb[i];
        whist[0][tid] = 0; whist[1][tid] = 0; whist[2][tid] = 0; whist[3][tid] = 0;
        __syncthreads();
        unsigned long long m = ~0ull;
#pragma unroll
        for (int bit = 0; bit < 8; ++bit) {
            const unsigned long long bb = __ballot((b >> bit) & 1);
            m &= ((b >> bit) & 1) ? bb : ~bb;
        }
        const unsigned long long ltmask = (lane == 63) ? ~0ull >> 1
                                         : ((1ull << lane) - 1);
        const int rank_in_wave = __popcll(m & ltmask);
        if (rank_in_wave == 0)
            whist[w][b] = (unsigned short)__popcll(m);
        __syncthreads();
        int rank = rank_in_wave;
#pragma unroll
        for (int ww = 0; ww < 3; ++ww)
            if (ww < w) rank += whist[ww][b];
        const int pos = base[b] + rank;
        sl[pos] = (unsigned short)i;
        __syncthreads();
        base[tid] += whist[0][tid] + whist[1][tid] + whist[2][tid] + whist[3][tid];
        __syncthreads();
    }

    for (int i = tid; i < 8192; i += 256)
        sorted[(size_t)bh * 8192 + i] = (int)sl[i];
}

// ---------------------------------------------------------------------------
// Kernel 4: MFMA fused chunked attention. One block per (b,h,chunk).
// Stages bf16 qk rows from qkb (straight copies; bytes identical to the old
// in-kernel f2bf) and loads precomputed row sumsq from ssqo.
// ---------------------------------------------------------------------------
#define KQP 72    // kq pitch (shorts): 144B rows, 16B-aligned, 2-way banks
#define VPP 136   // vvt/Pm pitch (shorts): 272B rows, 16B-aligned, 2-way banks

__global__ __launch_bounds__(256)
void attn_kernel(const unsigned short* __restrict__ qkb,
                 const float* __restrict__ ssqo,
                 const unsigned short* __restrict__ vb,
                 const int* __restrict__ sorted,
                 unsigned short* __restrict__ out_hash,
                 float* __restrict__ logits)
{
    __shared__ unsigned short kq[128 * KQP];   // bf16 qk rows (keys 0-127; queries = rows 64-127)
    __shared__ unsigned short vvt[64 * VPP];   // bf16 v transposed [d][key]
    __shared__ unsigned short Pm[64 * VPP];    // bf16 probs [q][key]
    __shared__ float scl[128];
    __shared__ unsigned short stick[128];
    __shared__ unsigned short qtick_lo[64];    // tk & 4095
    __shared__ unsigned short qtick_hi[64];    // tk >> 12
    __shared__ float lg[64];

    const int tid = threadIdx.x;
    const int c  = blockIdx.x;
    const int bh = blockIdx.z * 16 + blockIdx.y;
    const int pc = (c + 127) & 127;

    if (tid < 128) {
        const int p  = (tid < 64) ? (pc * 64 + tid) : (c * 64 + (tid - 64));
        const int tk = sorted[(size_t)bh * 8192 + p];
        stick[tid] = (unsigned short)(tk & 4095);
        if (tid >= 64) {
            qtick_lo[tid - 64] = (unsigned short)(tk & 4095);
            qtick_hi[tid - 64] = (unsigned short)(tk >> 12);
        }
    }
    __syncthreads();

    // ---- staging: bf16 qk rows -> kq (copies), v rows -> vvt^T; scl ----
    {
        const int r = tid >> 1, half = tid & 1;
        const int srow = stick[r];
        const u16x8* src = (const u16x8*)(qkb + (((size_t)bh * 4096 + srow) << 6) + half * 32);
#pragma unroll
        for (int i = 0; i < 4; ++i)
            *(u16x8*)&kq[r * KQP + half * 32 + i * 8] = src[i];

        const unsigned short* vs = vb + (((size_t)bh * 4096 + srow) << 6) + half * 32;
        unsigned short vtmp[32];
#pragma unroll
        for (int i = 0; i < 4; ++i)
            *(u16x8*)&vtmp[i * 8] = *(const u16x8*)(vs + i * 8);
#pragma unroll
        for (int j = 0; j < 32; ++j)
            vvt[(half * 32 + j) * VPP + r] = vtmp[j];
    }
    if (tid < 128) {
        const float ss = ssqo[(size_t)bh * 4096 + stick[tid]];
        scl[tid] = (1.0f / sqrtf(ss * (1.0f / 64.0f) + 1e-6f)) * 0.125f;
    }
    __syncthreads();

    const int w    = tid >> 6;          // wave -> q-strip [w*16, w*16+16)
    const int lane = tid & 63;
    const int l16  = lane & 15;
    const int quad = lane >> 4;

    // ---- QK^T: 16 MFMA per wave ----
    f32x4 accS[8];
#pragma unroll
    for (int t = 0; t < 8; ++t) accS[t] = f32x4{0.f, 0.f, 0.f, 0.f};
#pragma unroll
    for (int kst = 0; kst < 2; ++kst) {
        const bf16x8 aq = *(const bf16x8*)&kq[(64 + w * 16 + l16) * KQP + kst * 32 + quad * 8];
#pragma unroll
        for (int t = 0; t < 8; ++t) {
            const bf16x8 bk = *(const bf16x8*)&kq[(t * 16 + l16) * KQP + kst * 32 + quad * 8];
            accS[t] = __builtin_amdgcn_mfma_f32_16x16x32_bf16(aq, bk, accS[t], 0, 0, 0);
        }
    }

    // ---- scale + mask + softmax (in-register, 16-lane reduce) ----
    float sct[8]; int tkt[8];
#pragma unroll
    for (int t = 0; t < 8; ++t) {
        sct[t] = scl[t * 16 + l16];
        tkt[t] = (int)stick[t * 16 + l16];
    }
    int tqr[4];
#pragma unroll
    for (int r = 0; r < 4; ++r) tqr[r] = (int)stick[64 + w * 16 + quad * 4 + r];

    float val[8][4];
#pragma unroll
    for (int t = 0; t < 8; ++t)
#pragma unroll
        for (int r = 0; r < 4; ++r) {
            float a = accS[t][r] * sct[t];
            if (tqr[r] <  tkt[t]) a = -1e9f;
            if (tqr[r] == tkt[t]) a = -1e5f;
            val[t][r] = a;
        }

    float inv_r[4], logit_r[4];
#pragma unroll
    for (int r = 0; r < 4; ++r) {
        float m = val[0][r];
#pragma unroll
        for (int t = 1; t < 8; ++t) m = fmaxf(m, val[t][r]);
        m = fmaxf(m, __shfl_xor(m, 1));
        m = fmaxf(m, __shfl_xor(m, 2));
        m = fmaxf(m, __shfl_xor(m, 4));
        m = fmaxf(m, __shfl_xor(m, 8));
        float l = 0.f;
#pragma unroll
        for (int t = 0; t < 8; ++t) { val[t][r] = expf(val[t][r] - m); l += val[t][r]; }
        l += __shfl_xor(l, 1);
        l += __shfl_xor(l, 2);
        l += __shfl_xor(l, 4);
        l += __shfl_xor(l, 8);
        logit_r[r] = m + logf(l);
        inv_r[r]   = 1.0f / l;
    }

    // P (bf16) to LDS in [q][key] layout; logits to LDS
#pragma unroll
    for (int t = 0; t < 8; ++t)
#pragma unroll
        for (int r = 0; r < 4; ++r)
            Pm[(w * 16 + quad * 4 + r) * VPP + t * 16 + l16] = f2bf(val[t][r] * inv_r[r]);
    if (l16 == 0) {
#pragma unroll
        for (int r = 0; r < 4; ++r) lg[w * 16 + quad * 4 + r] = logit_r[r];
    }
    __syncthreads();

    // ---- PV: 16 MFMA per wave ----
    f32x4 accO[4];
#pragma unroll
    for (int dt = 0; dt < 4; ++dt) accO[dt] = f32x4{0.f, 0.f, 0.f, 0.f};
#pragma unroll
    for (int kst = 0; kst < 4; ++kst) {
        const bf16x8 ap = *(const bf16x8*)&Pm[(w * 16 + l16) * VPP + kst * 32 + quad * 8];
#pragma unroll
        for (int dt = 0; dt < 4; ++dt) {
            const bf16x8 bv = *(const bf16x8*)&vvt[(dt * 16 + l16) * VPP + kst * 32 + quad * 8];
            accO[dt] = __builtin_amdgcn_mfma_f32_16x16x32_bf16(ap, bv, accO[dt], 0, 0, 0);
        }
    }

    // ---- output: bf16 via LDS (reuse kq as outb [64][KQP]) ----
    unsigned short* outb = kq;   // all kq reads completed before Pm barrier
#pragma unroll
    for (int dt = 0; dt < 4; ++dt)
#pragma unroll
        for (int r = 0; r < 4; ++r)
            outb[(w * 16 + quad * 4 + r) * KQP + dt * 16 + l16] = f2bf(accO[dt][r]);
    __syncthreads();

    if (tid < 64) {
        const int n = qtick_hi[tid], s = qtick_lo[tid];
        logits[((size_t)bh * 2 + n) * 4096 + s] = lg[tid];
    }
    {
        const int qq = tid >> 2, part = tid & 3;
        const int n = qtick_hi[qq], s = qtick_lo[qq];
        const size_t ob = (((size_t)bh * 2 + n) * 4096 + s) * 64 + part * 16;
        u16x8 u0 = *(const u16x8*)&outb[qq * KQP + part * 16];
        u16x8 u1 = *(const u16x8*)&outb[qq * KQP + part * 16 + 8];
        *(u16x8*)(out_hash + ob)     = u0;
        *(u16x8*)(out_hash + ob + 8) = u1;
    }
}

// ---------------------------------------------------------------------------
// Kernel 5: combine hash rounds with logsumexp weights; emit fp32 [B,S,H*D].
// ---------------------------------------------------------------------------
__global__ __launch_bounds__(256)
void combine_kernel(const unsigned short* __restrict__ out_hash,
                    const float* __restrict__ logits,
                    float* __restrict__ out)
{
    const int idx  = blockIdx.x * 256 + threadIdx.x;   // < 2097152
    const int bh   = idx >> 16;
    const int rem  = idx & 65535;
    const int s    = rem >> 4;
    const int part = rem & 15;
    const float lg0 = logits[((size_t)bh * 2 + 0) * 4096 + s];
    const float lg1 = logits[((size_t)bh * 2 + 1) * 4096 + s];
    const float m  = fmaxf(lg0, lg1);
    const float e0 = expf(lg0 - m), e1 = expf(lg1 - m);
    const float inv = 1.0f / (e0 + e1);
    const float w0 = e0 * inv, w1 = e1 * inv;
    const size_t b0 = (((size_t)bh * 2 + 0) * 4096 + s) * 64 + part * 4;
    const size_t b1 = (((size_t)bh * 2 + 1) * 4096 + s) * 64 + part * 4;
    u16x4 u0 = *(const u16x4*)(out_hash + b0);
    u16x4 u1 = *(const u16x4*)(out_hash + b1);
    const int b = bh >> 4, hh = bh & 15;
    const size_t ob = ((size_t)b * 4096 + s) * 1024 + hh * 64 + part * 4;
    f32x4 r;
#pragma unroll
    for (int e = 0; e < 4; ++e)
        r[e] = w0 * bf2f(u0[e]) + w1 * bf2f(u1[e]);
    *(f32x4*)(out + ob) = r;
}

// ---------------------------------------------------------------------------
extern "C" void kernel_launch(void* const* d_in, const int* in_sizes, int n_in,
                              void* d_out, int out_size, void* d_ws, size_t ws_size,
                              hipStream_t stream) {
    const float* hidden = (const float*)d_in[0];   // [2,4096,1024] fp32
    const float* wqk    = (const float*)d_in[1];   // [1024,1024]   fp32
    const float* wv     = (const float*)d_in[2];   // [1024,1024]   fp32
    const float* rotf   = (const float*)d_in[3];   // [64,2,64]     fp32
    float* out = (float*)d_out;                    // [2,4096,1024] fp32

    char* ws = (char*)d_ws;
    float*          qk       = (float*)(ws);                       // 33,554,432 B
    unsigned short* vb       = (unsigned short*)(ws + 33554432);   // 16,777,216 B
    int*            buckets  = (int*)(ws + 50331648);              //  1,048,576 B
    int*            sorted   = (int*)(ws + 51380224);              //  1,048,576 B
    float*          logits   = (float*)(ws + 52428800);            //  1,048,576 B
    unsigned short* out_hash = (unsigned short*)(ws + 53477376);   // 33,554,432 B
    // hidden hi/lo splits ALIAS out_hash: they are consumed by gemm_v, which
    // completes before attn_kernel (the only writer of out_hash). Stream order
    // serializes qk_split(write) -> gemm_v(read) -> attn(write).
    unsigned short* hH = out_hash;                                 // 16,777,216 B
    unsigned short* hL = out_hash + 8388608;                       // 16,777,216 B
    unsigned short* wH = (unsigned short*)(ws + 87031808);         //  2,097,152 B
    unsigned short* wL = (unsigned short*)(ws + 89128960);         //  2,097,152 B
    unsigned short* qkb = (unsigned short*)(ws + 91226112);        // 16,777,216 B
    float*          ssqo = (float*)(ws + 108003328);               //    524,288 B
    // total 108,527,616 B

    hipLaunchKernelGGL(gemm_qk_split, dim3(9728), dim3(256), 0, stream,
                       hidden, wqk, qk, qkb, ssqo, wv, hH, hL, wH, wL);
    hipLaunchKernelGGL(gemm_v,      dim3(64, 8),   dim3(256), 0, stream,
                       hH, hL, wH, wL, vb);
    hipLaunchKernelGGL(hash_kernel, dim3(2048),    dim3(256), 0, stream,
                       qk, rotf, buckets);
    hipLaunchKernelGGL(sort_kernel, dim3(32),      dim3(256), 0, stream,
                       buckets, sorted);
    hipLaunchKernelGGL(attn_kernel, dim3(128, 16, 2), dim3(256), 0, stream,
                       qkb, ssqo, vb, sorted, out_hash, logits);
    hipLaunchKernelGGL(combine_kernel, dim3(8192), dim3(256), 0, stream,
                       out_hash, logits, out);
}

// Round 14
// 511.470 us; speedup vs baseline: 1.0059x; 1.0059x over previous
//
#include <hip/hip_runtime.h>

// ---------------------------------------------------------------------------
// LSH self-attention (Reformer). B=2,S=4096,H=16,D=64,NH=2,NB=128,CHUNK=64,
// N_BEFORE=1. Inputs fp32, output fp32.
// Precision-critical path (qk projection + hash einsum feeding argmax) is
// fp32 with sequential ascending-k FMA chains (matches np/BLAS order).
// Attention on bf16 MFMA (smooth path). v projection: bf16x2-split MFMA GEMM.
// gemm_qk history: R1 conflict fix 238->225; R4 8x8/128x128: 224 = source
//   ceiling for sequential-k fp32 (R5/R6/R7 regressed).
// R8: split folded into qk dispatch (trailing streamer blocks), total 513.3.
// R11/R12: qkb bf16 copy + ssqo sumsq from qk epilogue; attn stages via
//   straight copies. attn -19us, qk +19us (qkb writes + epilogue serial,
//   NOT LDS capacity — R12 disproved that). Net wash (513.3/513.9/514.5).
//   Keeping R12 design; stop trading qk<->attn.
// R13: sort split per hash round. Hash0 elems (idx 0..4095) have buckets
//   <128, hash1 (4096..8191) >=128, exactly 4096 each -> stable sort of
//   8192 = concat of stable sorts of halves. 32->64 blocks, serial chunk
//   chain 32->16 iters. Per-half 256-counter scan unchanged (other half's
//   counters are zero); writeback adds half offset. sorted bit-identical.
// ---------------------------------------------------------------------------

typedef __attribute__((ext_vector_type(4))) float          f32x4;
typedef __attribute__((ext_vector_type(4))) unsigned short u16x4;
typedef __attribute__((ext_vector_type(8))) unsigned short u16x8;
typedef __attribute__((ext_vector_type(8))) __bf16         bf16x8;

__device__ __forceinline__ float bf2f(unsigned short u) {
    unsigned int x = ((unsigned int)u) << 16;
    return __builtin_bit_cast(float, x);
}
__device__ __forceinline__ unsigned short f2bf(float f) {
    unsigned int x = __builtin_bit_cast(unsigned int, f);
    x += 0x7FFFu + ((x >> 16) & 1u);
    return (unsigned short)(x >> 16);
}

// async global->LDS, 16B per lane, wave-uniform LDS base (HW adds lane*16).
__device__ __forceinline__ void gll16(const unsigned short* g, unsigned short* l) {
    __builtin_amdgcn_global_load_lds(
        (__attribute__((address_space(1))) void*)(g),
        (__attribute__((address_space(3))) void*)(l),
        16, 0, 0);
}

// ---------------------------------------------------------------------------
// Kernel 1a: qk projection (R4-exact core) + hidden/wv hi-lo split as
// trailing blocks. Blocks 0..511: qk 128x128 tile, 8x8/thread, fp32
// sequential ascending-k FMA — DO NOT change accumulation order (argmax).
// Epilogue emits bf16 qk copy (qkb) + per-row sumsq (ssqo); sumsq scratch
// aliases the dead As/Bs LDS. Blocks 512..9727: split streamer.
// ---------------------------------------------------------------------------
__global__ __launch_bounds__(256)
void gemm_qk_split(const float* __restrict__ hidden,
                   const float* __restrict__ wqk,
                   float* __restrict__ qk_out,
                   unsigned short* __restrict__ qkb,
                   float* __restrict__ ssqo,
                   const float* __restrict__ wv,
                   unsigned short* __restrict__ hH, unsigned short* __restrict__ hL,
                   unsigned short* __restrict__ wH, unsigned short* __restrict__ wL)
{
    __shared__ __attribute__((aligned(16))) char qsmem[16896];  // As|Bs, later ssq
    float (*As)[132] = (float(*)[132])qsmem;            //  8448 B
    float (*Bs)[132] = (float(*)[132])(qsmem + 8448);   //  8448 B
    const int tid = threadIdx.x;

    if (blockIdx.x >= 512) {
        // ---- split path: hidden (2097152 vec4) then wv (262144 vec4) ----
        const int idx = (blockIdx.x - 512) * 256 + tid;    // < 2359296
        const bool isw = idx >= 2097152;
        const float* src = isw ? wv : hidden;
        unsigned short* dh = isw ? wH : hH;
        unsigned short* dl = isw ? wL : hL;
        const int v = isw ? (idx - 2097152) : idx;
        const f32x4 x = *((const f32x4*)src + v);
        u16x4 h, l;
#pragma unroll
        for (int j = 0; j < 4; ++j) {
            const unsigned short hs = f2bf(x[j]);
            h[j] = hs;
            l[j] = f2bf(x[j] - bf2f(hs));   // x - bf2f(hi) exact (Sterbenz)
        }
        *((u16x4*)dh + v) = h;
        *((u16x4*)dl + v) = l;
        return;
    }

    // ---- qk path (R4-exact main loop) ----
    const int bm  = blockIdx.x & 63;    // 0..63
    const int bn  = blockIdx.x >> 6;    // 0..7

    const float* Asrc = hidden + (size_t)bm * 128 * 1024;
    const float* Bsrc = wqk + (size_t)bn * 128 * 1024;

    const int mlo = (tid & 15) * 4;     // A-read base (16B-stride, 2-way free)
    const int nlo = (tid >> 4) * 4;     // B-read base (broadcast groups)

    float acc[8][8];
#pragma unroll
    for (int r = 0; r < 8; ++r)
#pragma unroll
        for (int c = 0; c < 8; ++c) acc[r][c] = 0.f;

    int srow[2], skof[2];
#pragma unroll
    for (int i = 0; i < 2; ++i) {
        const int c = i * 256 + tid;
        srow[i] = c >> 2;
        skof[i] = (c & 3) * 4;
    }

    f32x4 apre[2], bpre[2];
#pragma unroll
    for (int i = 0; i < 2; ++i) {
        apre[i] = *(const f32x4*)(Asrc + (size_t)srow[i] * 1024 + skof[i]);
        bpre[i] = *(const f32x4*)(Bsrc + (size_t)srow[i] * 1024 + skof[i]);
    }

    for (int ks = 0; ks < 64; ++ks) {   // K = 64 tiles * 16, ascending
#pragma unroll
        for (int i = 0; i < 2; ++i)
#pragma unroll
            for (int j = 0; j < 4; ++j) {
                As[skof[i] + j][srow[i]] = apre[i][j];
                Bs[skof[i] + j][srow[i]] = bpre[i][j];
            }
        __syncthreads();
        if (ks < 63) {
            const int k0 = (ks + 1) * 16;
#pragma unroll
            for (int i = 0; i < 2; ++i) {
                apre[i] = *(const f32x4*)(Asrc + (size_t)srow[i] * 1024 + k0 + skof[i]);
                bpre[i] = *(const f32x4*)(Bsrc + (size_t)srow[i] * 1024 + k0 + skof[i]);
            }
        }
#pragma unroll
        for (int k = 0; k < 16; ++k) {
            f32x4 a0 = *(const f32x4*)&As[k][mlo];
            f32x4 a1 = *(const f32x4*)&As[k][64 + mlo];
            f32x4 b0 = *(const f32x4*)&Bs[k][nlo];
            f32x4 b1 = *(const f32x4*)&Bs[k][64 + nlo];
#pragma unroll
            for (int c = 0; c < 4; ++c) {
#pragma unroll
                for (int r = 0; r < 4; ++r) {
                    acc[r][c]         = __builtin_fmaf(a0[r], b0[c], acc[r][c]);
                    acc[r][c + 4]     = __builtin_fmaf(a0[r], b1[c], acc[r][c + 4]);
                    acc[r + 4][c]     = __builtin_fmaf(a1[r], b0[c], acc[r + 4][c]);
                    acc[r + 4][c + 4] = __builtin_fmaf(a1[r], b1[c], acc[r + 4][c + 4]);
                }
            }
        }
        __syncthreads();
    }

    // ---- epilogue. As/Bs dead past the final barrier: reuse as ssq ----
    float* ssq = (float*)qsmem;          // [16][256] partials, 16384 B

#pragma unroll
    for (int r = 0; r < 8; ++r) {
        const int mm = (r < 4) ? (mlo + r) : (64 + mlo + (r - 4));
#pragma unroll
        for (int g = 0; g < 2; ++g) {
            float p = acc[r][g * 4 + 0] * acc[r][g * 4 + 0];
            p = __builtin_fmaf(acc[r][g * 4 + 1], acc[r][g * 4 + 1], p);
            p = __builtin_fmaf(acc[r][g * 4 + 2], acc[r][g * 4 + 2], p);
            p = __builtin_fmaf(acc[r][g * 4 + 3], acc[r][g * 4 + 3], p);
            ssq[(tid >> 4) * 256 + mm * 2 + g] = p;
        }
    }

#pragma unroll
    for (int r = 0; r < 8; ++r) {
        const int mm = (r < 4) ? (mlo + r) : (64 + mlo + (r - 4));
        const int m  = bm * 128 + mm;
        const int bb = m >> 12, s = m & 4095;
#pragma unroll
        for (int g = 0; g < 2; ++g) {
            const int n  = bn * 128 + (g ? (64 + nlo) : nlo);   // 4-aligned
            const int hh = n >> 6, d = n & 63;
            f32x4 v;
            u16x4 hb;
#pragma unroll
            for (int c = 0; c < 4; ++c) { v[c] = acc[r][g * 4 + c]; hb[c] = f2bf(v[c]); }
            const size_t ob = (((size_t)(bb * 16 + hh)) * 4096 + s) * 64 + d;
            *(f32x4*)&qk_out[ob] = v;
            *(u16x4*)&qkb[ob]    = hb;
        }
    }

    __syncthreads();
    {
        // 256 threads: one (row, g) each. Reads conflict-free (consecutive).
        const int rw = tid >> 1, g = tid & 1;
        float tot = 0.f;
#pragma unroll
        for (int i = 0; i < 16; ++i) tot += ssq[i * 256 + tid];
        const int m  = bm * 128 + rw;
        const int bb = m >> 12, s = m & 4095;
        const int hh = bn * 2 + g;
        ssqo[((size_t)(bb * 16 + hh)) * 4096 + s] = tot;
    }
}

// ---------------------------------------------------------------------------
// Kernel 1b: v projection as bf16x2-split MFMA GEMM.
// C[m][n] = sum_k (Ah+Al)[m][k] * (Bh+Bl)[n][k], dropping Al*Bl (~2^-18 rel).
// BM=128, BN=128, BK=32, 4 waves, each wave owns a 64x64 quadrant.
// ---------------------------------------------------------------------------
__global__ __launch_bounds__(256)
void gemm_v(const unsigned short* __restrict__ hH,
            const unsigned short* __restrict__ hL,
            const unsigned short* __restrict__ wH,
            const unsigned short* __restrict__ wL,
            unsigned short* __restrict__ v_out)
{
    __shared__ __attribute__((aligned(16))) unsigned short Ah[128 * 32];
    __shared__ __attribute__((aligned(16))) unsigned short Al[128 * 32];
    __shared__ __attribute__((aligned(16))) unsigned short Bh[128 * 32];
    __shared__ __attribute__((aligned(16))) unsigned short Bl[128 * 32];

    const int tid  = threadIdx.x;
    const int bm   = blockIdx.x;          // 0..63  (M = 8192)
    const int bn   = blockIdx.y;          // 0..7   (N = 1024)
    const int w    = tid >> 6;
    const int lane = tid & 63;
    const int l16  = lane & 15;
    const int quad = lane >> 4;
    const int m0   = (w >> 1) * 64;
    const int n0   = (w & 1) * 64;

    const int c0 = w * 2;
    const int r0 = c0 * 16 + (lane >> 2);   // tile row for chunk c0
    const int r1 = r0 + 16;                 // tile row for chunk c0+1
    const int kf = (lane & 3) * 8;          // k offset in shorts

    const size_t abase = (size_t)bm * 128 * 1024;   // shorts
    const size_t bbase = (size_t)bn * 128 * 1024;

    f32x4 acc[4][4];
#pragma unroll
    for (int i = 0; i < 4; ++i)
#pragma unroll
        for (int j = 0; j < 4; ++j) acc[i][j] = f32x4{0.f, 0.f, 0.f, 0.f};

    for (int ks = 0; ks < 32; ++ks) {
        const int kb = ks * 32 + kf;
        gll16(hH + abase + (size_t)r0 * 1024 + kb, Ah + (size_t)c0 * 512);
        gll16(hH + abase + (size_t)r1 * 1024 + kb, Ah + (size_t)(c0 + 1) * 512);
        gll16(hL + abase + (size_t)r0 * 1024 + kb, Al + (size_t)c0 * 512);
        gll16(hL + abase + (size_t)r1 * 1024 + kb, Al + (size_t)(c0 + 1) * 512);
        gll16(wH + bbase + (size_t)r0 * 1024 + kb, Bh + (size_t)c0 * 512);
        gll16(wH + bbase + (size_t)r1 * 1024 + kb, Bh + (size_t)(c0 + 1) * 512);
        gll16(wL + bbase + (size_t)r0 * 1024 + kb, Bl + (size_t)c0 * 512);
        gll16(wL + bbase + (size_t)r1 * 1024 + kb, Bl + (size_t)(c0 + 1) * 512);
        __syncthreads();   // drains vmcnt (global_load_lds) + barrier

        bf16x8 ahf[4], alf[4], bhf[4], blf[4];
#pragma unroll
        for (int i = 0; i < 4; ++i) {
            ahf[i] = *(const bf16x8*)&Ah[(m0 + i * 16 + l16) * 32 + quad * 8];
            alf[i] = *(const bf16x8*)&Al[(m0 + i * 16 + l16) * 32 + quad * 8];
        }
#pragma unroll
        for (int j = 0; j < 4; ++j) {
            bhf[j] = *(const bf16x8*)&Bh[(n0 + j * 16 + l16) * 32 + quad * 8];
            blf[j] = *(const bf16x8*)&Bl[(n0 + j * 16 + l16) * 32 + quad * 8];
        }
#pragma unroll
        for (int i = 0; i < 4; ++i)
#pragma unroll
            for (int j = 0; j < 4; ++j) {
                acc[i][j] = __builtin_amdgcn_mfma_f32_16x16x32_bf16(ahf[i], bhf[j], acc[i][j], 0, 0, 0);
                acc[i][j] = __builtin_amdgcn_mfma_f32_16x16x32_bf16(alf[i], bhf[j], acc[i][j], 0, 0, 0);
                acc[i][j] = __builtin_amdgcn_mfma_f32_16x16x32_bf16(ahf[i], blf[j], acc[i][j], 0, 0, 0);
            }
        __syncthreads();   // tile fully consumed before next stage overwrites
    }

    // C/D layout [m89]: col = lane&15 (n index), row = quad*4 + reg (m index)
#pragma unroll
    for (int i = 0; i < 4; ++i) {
#pragma unroll
        for (int r = 0; r < 4; ++r) {
            const int m  = bm * 128 + m0 + i * 16 + quad * 4 + r;
            const int bb = m >> 12, s = m & 4095;
#pragma unroll
            for (int j = 0; j < 4; ++j) {
                const int n  = bn * 128 + n0 + j * 16 + l16;
                const int hh = n >> 6, d = n & 63;
                v_out[(((size_t)(bb * 16 + hh)) * 4096 + s) * 64 + d] = f2bf(acc[i][j][r]);
            }
        }
    }
}

// ---------------------------------------------------------------------------
// Kernel 2: hashing. Sequential ascending-d fp32 FMA; argmax over
// concat(rot,-rot), first-occurrence ties. One wave per row-group.
// Reads fp32 qk (exact — buckets must not change).
// ---------------------------------------------------------------------------
__global__ __launch_bounds__(256)
void hash_kernel(const float* __restrict__ qk,
                 const float* __restrict__ rotf,
                 int* __restrict__ buckets)
{
    __shared__ float rot[8192];       // [d][n*64+r]
    __shared__ float rows[64 * 64];
    const int tid = threadIdx.x;
    for (int i = tid; i < 8192; i += 256) rot[i] = rotf[i];
    const int rbase = blockIdx.x * 64;
    {
        const f32x4* src = (const f32x4*)(qk + (size_t)rbase * 64);
        f32x4* dst = (f32x4*)rows;
#pragma unroll
        for (int i = 0; i < 4; ++i) dst[tid + i * 256] = src[tid + i * 256];
    }
    __syncthreads();
    const int w = tid >> 6, lane = tid & 63;
    for (int rr = 0; rr < 16; ++rr) {
        const int row = w * 16 + rr;
        float a0 = 0.f, a1 = 0.f;
#pragma unroll
        for (int dg = 0; dg < 16; ++dg) {
            f32x4 qb = *(const f32x4*)&rows[row * 64 + dg * 4];
#pragma unroll
            for (int j = 0; j < 4; ++j) {
                const int d = dg * 4 + j;
                a0 = __builtin_fmaf(qb[j], rot[d * 128 + lane],      a0);
                a1 = __builtin_fmaf(qb[j], rot[d * 128 + 64 + lane], a1);
            }
        }
        float v0, v1; int i0, i1;
        if (a0 >= -a0) { v0 = a0;  i0 = lane; } else { v0 = -a0; i0 = 64 + lane; }
        if (a1 >= -a1) { v1 = a1;  i1 = lane; } else { v1 = -a1; i1 = 64 + lane; }
#pragma unroll
        for (int m = 1; m < 64; m <<= 1) {
            float ov = __shfl_xor(v0, m); int oi = __shfl_xor(i0, m);
            if (ov > v0 || (ov == v0 && oi < i0)) { v0 = ov; i0 = oi; }
            ov = __shfl_xor(v1, m); oi = __shfl_xor(i1, m);
            if (ov > v1 || (ov == v1 && oi < i1)) { v1 = ov; i1 = oi; }
        }
        if (lane == 0) {
            const int g = rbase + row;
            const int bh = g >> 12, s = g & 4095;
            buckets[(size_t)bh * 8192 + s]        = i0;          // hash 0
            buckets[(size_t)bh * 8192 + 4096 + s] = i1 + 128;    // hash 1
        }
    }
}

// ---------------------------------------------------------------------------
// Kernel 3: stable counting sort, split per (b,h,hash). 64 blocks.
// Hash0 elems (0..4095, buckets<128) and hash1 (4096..8191, buckets>=128)
// sort independently; concat == original stable sort (bit-identical).
// ---------------------------------------------------------------------------
__global__ __launch_bounds__(256)
void sort_kernel(const int* __restrict__ buckets, int* __restrict__ sorted)
{
    __shared__ unsigned char  lb[4096];
    __shared__ unsigned short sl[4096];
    __shared__ int cnt[256];
    __shared__ int base[256];
    __shared__ unsigned short whist[4][256];
    const int tid  = threadIdx.x;
    const int bh   = blockIdx.x >> 1;
    const int hoff = (blockIdx.x & 1) * 4096;   // hash-half offset
    const int lane = tid & 63;
    const int w    = tid >> 6;

    cnt[tid] = 0;
    for (int i = tid; i < 4096; i += 256)
        lb[i] = (unsigned char)buckets[(size_t)bh * 8192 + hoff + i];
    __syncthreads();
    for (int i = tid; i < 4096; i += 256) atomicAdd(&cnt[lb[i]], 1);
    __syncthreads();

    base[tid] = cnt[tid];
    __syncthreads();
#pragma unroll
    for (int off = 1; off < 256; off <<= 1) {
        int t = (tid >= off) ? base[tid - off] : 0;
        __syncthreads();
        base[tid] += t;
        __syncthreads();
    }
    {
        int ex = base[tid] - cnt[tid];
        __syncthreads();
        base[tid] = ex;
        __syncthreads();
    }

    for (int c = 0; c < 16; ++c) {
        const int i = c * 256 + tid;
        const int b = lb[i];
        whist[0][tid] = 0; whist[1][tid] = 0; whist[2][tid] = 0; whist[3][tid] = 0;
        __syncthreads();
        unsigned long long m = ~0ull;
#pragma unroll
        for (int bit = 0; bit < 8; ++bit) {
            const unsigned long long bb = __ballot((b >> bit) & 1);
            m &= ((b >> bit) & 1) ? bb : ~bb;
        }
        const unsigned long long ltmask = (lane == 63) ? ~0ull >> 1
                                         : ((1ull << lane) - 1);
        const int rank_in_wave = __popcll(m & ltmask);
        if (rank_in_wave == 0)
            whist[w][b] = (unsigned short)__popcll(m);
        __syncthreads();
        int rank = rank_in_wave;
#pragma unroll
        for (int ww = 0; ww < 3; ++ww)
            if (ww < w) rank += whist[ww][b];
        const int pos = base[b] + rank;
        sl[pos] = (unsigned short)i;
        __syncthreads();
        base[tid] += whist[0][tid] + whist[1][tid] + whist[2][tid] + whist[3][tid];
        __syncthreads();
    }

    for (int i = tid; i < 4096; i += 256)
        sorted[(size_t)bh * 8192 + hoff + i] = hoff + (int)sl[i];
}

// ---------------------------------------------------------------------------
// Kernel 4: MFMA fused chunked attention. One block per (b,h,chunk).
// Stages bf16 qk rows from qkb (straight copies; bytes identical to the old
// in-kernel f2bf) and loads precomputed row sumsq from ssqo.
// ---------------------------------------------------------------------------
#define KQP 72    // kq pitch (shorts): 144B rows, 16B-aligned, 2-way banks
#define VPP 136   // vvt/Pm pitch (shorts): 272B rows, 16B-aligned, 2-way banks

__global__ __launch_bounds__(256)
void attn_kernel(const unsigned short* __restrict__ qkb,
                 const float* __restrict__ ssqo,
                 const unsigned short* __restrict__ vb,
                 const int* __restrict__ sorted,
                 unsigned short* __restrict__ out_hash,
                 float* __restrict__ logits)
{
    __shared__ unsigned short kq[128 * KQP];   // bf16 qk rows (keys 0-127; queries = rows 64-127)
    __shared__ unsigned short vvt[64 * VPP];   // bf16 v transposed [d][key]
    __shared__ unsigned short Pm[64 * VPP];    // bf16 probs [q][key]
    __shared__ float scl[128];
    __shared__ unsigned short stick[128];
    __shared__ unsigned short qtick_lo[64];    // tk & 4095
    __shared__ unsigned short qtick_hi[64];    // tk >> 12
    __shared__ float lg[64];

    const int tid = threadIdx.x;
    const int c  = blockIdx.x;
    const int bh = blockIdx.z * 16 + blockIdx.y;
    const int pc = (c + 127) & 127;

    if (tid < 128) {
        const int p  = (tid < 64) ? (pc * 64 + tid) : (c * 64 + (tid - 64));
        const int tk = sorted[(size_t)bh * 8192 + p];
        stick[tid] = (unsigned short)(tk & 4095);
        if (tid >= 64) {
            qtick_lo[tid - 64] = (unsigned short)(tk & 4095);
            qtick_hi[tid - 64] = (unsigned short)(tk >> 12);
        }
    }
    __syncthreads();

    // ---- staging: bf16 qk rows -> kq (copies), v rows -> vvt^T; scl ----
    {
        const int r = tid >> 1, half = tid & 1;
        const int srow = stick[r];
        const u16x8* src = (const u16x8*)(qkb + (((size_t)bh * 4096 + srow) << 6) + half * 32);
#pragma unroll
        for (int i = 0; i < 4; ++i)
            *(u16x8*)&kq[r * KQP + half * 32 + i * 8] = src[i];

        const unsigned short* vs = vb + (((size_t)bh * 4096 + srow) << 6) + half * 32;
        unsigned short vtmp[32];
#pragma unroll
        for (int i = 0; i < 4; ++i)
            *(u16x8*)&vtmp[i * 8] = *(const u16x8*)(vs + i * 8);
#pragma unroll
        for (int j = 0; j < 32; ++j)
            vvt[(half * 32 + j) * VPP + r] = vtmp[j];
    }
    if (tid < 128) {
        const float ss = ssqo[(size_t)bh * 4096 + stick[tid]];
        scl[tid] = (1.0f / sqrtf(ss * (1.0f / 64.0f) + 1e-6f)) * 0.125f;
    }
    __syncthreads();

    const int w    = tid >> 6;          // wave -> q-strip [w*16, w*16+16)
    const int lane = tid & 63;
    const int l16  = lane & 15;
    const int quad = lane >> 4;

    // ---- QK^T: 16 MFMA per wave ----
    f32x4 accS[8];
#pragma unroll
    for (int t = 0; t < 8; ++t) accS[t] = f32x4{0.f, 0.f, 0.f, 0.f};
#pragma unroll
    for (int kst = 0; kst < 2; ++kst) {
        const bf16x8 aq = *(const bf16x8*)&kq[(64 + w * 16 + l16) * KQP + kst * 32 + quad * 8];
#pragma unroll
        for (int t = 0; t < 8; ++t) {
            const bf16x8 bk = *(const bf16x8*)&kq[(t * 16 + l16) * KQP + kst * 32 + quad * 8];
            accS[t] = __builtin_amdgcn_mfma_f32_16x16x32_bf16(aq, bk, accS[t], 0, 0, 0);
        }
    }

    // ---- scale + mask + softmax (in-register, 16-lane reduce) ----
    float sct[8]; int tkt[8];
#pragma unroll
    for (int t = 0; t < 8; ++t) {
        sct[t] = scl[t * 16 + l16];
        tkt[t] = (int)stick[t * 16 + l16];
    }
    int tqr[4];
#pragma unroll
    for (int r = 0; r < 4; ++r) tqr[r] = (int)stick[64 + w * 16 + quad * 4 + r];

    float val[8][4];
#pragma unroll
    for (int t = 0; t < 8; ++t)
#pragma unroll
        for (int r = 0; r < 4; ++r) {
            float a = accS[t][r] * sct[t];
            if (tqr[r] <  tkt[t]) a = -1e9f;
            if (tqr[r] == tkt[t]) a = -1e5f;
            val[t][r] = a;
        }

    float inv_r[4], logit_r[4];
#pragma unroll
    for (int r = 0; r < 4; ++r) {
        float m = val[0][r];
#pragma unroll
        for (int t = 1; t < 8; ++t) m = fmaxf(m, val[t][r]);
        m = fmaxf(m, __shfl_xor(m, 1));
        m = fmaxf(m, __shfl_xor(m, 2));
        m = fmaxf(m, __shfl_xor(m, 4));
        m = fmaxf(m, __shfl_xor(m, 8));
        float l = 0.f;
#pragma unroll
        for (int t = 0; t < 8; ++t) { val[t][r] = expf(val[t][r] - m); l += val[t][r]; }
        l += __shfl_xor(l, 1);
        l += __shfl_xor(l, 2);
        l += __shfl_xor(l, 4);
        l += __shfl_xor(l, 8);
        logit_r[r] = m + logf(l);
        inv_r[r]   = 1.0f / l;
    }

    // P (bf16) to LDS in [q][key] layout; logits to LDS
#pragma unroll
    for (int t = 0; t < 8; ++t)
#pragma unroll
        for (int r = 0; r < 4; ++r)
            Pm[(w * 16 + quad * 4 + r) * VPP + t * 16 + l16] = f2bf(val[t][r] * inv_r[r]);
    if (l16 == 0) {
#pragma unroll
        for (int r = 0; r < 4; ++r) lg[w * 16 + quad * 4 + r] = logit_r[r];
    }
    __syncthreads();

    // ---- PV: 16 MFMA per wave ----
    f32x4 accO[4];
#pragma unroll
    for (int dt = 0; dt < 4; ++dt) accO[dt] = f32x4{0.f, 0.f, 0.f, 0.f};
#pragma unroll
    for (int kst = 0; kst < 4; ++kst) {
        const bf16x8 ap = *(const bf16x8*)&Pm[(w * 16 + l16) * VPP + kst * 32 + quad * 8];
#pragma unroll
        for (int dt = 0; dt < 4; ++dt) {
            const bf16x8 bv = *(const bf16x8*)&vvt[(dt * 16 + l16) * VPP + kst * 32 + quad * 8];
            accO[dt] = __builtin_amdgcn_mfma_f32_16x16x32_bf16(ap, bv, accO[dt], 0, 0, 0);
        }
    }

    // ---- output: bf16 via LDS (reuse kq as outb [64][KQP]) ----
    unsigned short* outb = kq;   // all kq reads completed before Pm barrier
#pragma unroll
    for (int dt = 0; dt < 4; ++dt)
#pragma unroll
        for (int r = 0; r < 4; ++r)
            outb[(w * 16 + quad * 4 + r) * KQP + dt * 16 + l16] = f2bf(accO[dt][r]);
    __syncthreads();

    if (tid < 64) {
        const int n = qtick_hi[tid], s = qtick_lo[tid];
        logits[((size_t)bh * 2 + n) * 4096 + s] = lg[tid];
    }
    {
        const int qq = tid >> 2, part = tid & 3;
        const int n = qtick_hi[qq], s = qtick_lo[qq];
        const size_t ob = (((size_t)bh * 2 + n) * 4096 + s) * 64 + part * 16;
        u16x8 u0 = *(const u16x8*)&outb[qq * KQP + part * 16];
        u16x8 u1 = *(const u16x8*)&outb[qq * KQP + part * 16 + 8];
        *(u16x8*)(out_hash + ob)     = u0;
        *(u16x8*)(out_hash + ob + 8) = u1;
    }
}

// ---------------------------------------------------------------------------
// Kernel 5: combine hash rounds with logsumexp weights; emit fp32 [B,S,H*D].
// ---------------------------------------------------------------------------
__global__ __launch_bounds__(256)
void combine_kernel(const unsigned short* __restrict__ out_hash,
                    const float* __restrict__ logits,
                    float* __restrict__ out)
{
    const int idx  = blockIdx.x * 256 + threadIdx.x;   // < 2097152
    const int bh   = idx >> 16;
    const int rem  = idx & 65535;
    const int s    = rem >> 4;
    const int part = rem & 15;
    const float lg0 = logits[((size_t)bh * 2 + 0) * 4096 + s];
    const float lg1 = logits[((size_t)bh * 2 + 1) * 4096 + s];
    const float m  = fmaxf(lg0, lg1);
    const float e0 = expf(lg0 - m), e1 = expf(lg1 - m);
    const float inv = 1.0f / (e0 + e1);
    const float w0 = e0 * inv, w1 = e1 * inv;
    const size_t b0 = (((size_t)bh * 2 + 0) * 4096 + s) * 64 + part * 4;
    const size_t b1 = (((size_t)bh * 2 + 1) * 4096 + s) * 64 + part * 4;
    u16x4 u0 = *(const u16x4*)(out_hash + b0);
    u16x4 u1 = *(const u16x4*)(out_hash + b1);
    const int b = bh >> 4, hh = bh & 15;
    const size_t ob = ((size_t)b * 4096 + s) * 1024 + hh * 64 + part * 4;
    f32x4 r;
#pragma unroll
    for (int e = 0; e < 4; ++e)
        r[e] = w0 * bf2f(u0[e]) + w1 * bf2f(u1[e]);
    *(f32x4*)(out + ob) = r;
}

// ---------------------------------------------------------------------------
extern "C" void kernel_launch(void* const* d_in, const int* in_sizes, int n_in,
                              void* d_out, int out_size, void* d_ws, size_t ws_size,
                              hipStream_t stream) {
    const float* hidden = (const float*)d_in[0];   // [2,4096,1024] fp32
    const float* wqk    = (const float*)d_in[1];   // [1024,1024]   fp32
    const float* wv     = (const float*)d_in[2];   // [1024,1024]   fp32
    const float* rotf   = (const float*)d_in[3];   // [64,2,64]     fp32
    float* out = (float*)d_out;                    // [2,4096,1024] fp32

    char* ws = (char*)d_ws;
    float*          qk       = (float*)(ws);                       // 33,554,432 B
    unsigned short* vb       = (unsigned short*)(ws + 33554432);   // 16,777,216 B
    int*            buckets  = (int*)(ws + 50331648);              //  1,048,576 B
    int*            sorted   = (int*)(ws + 51380224);              //  1,048,576 B
    float*          logits   = (float*)(ws + 52428800);            //  1,048,576 B
    unsigned short* out_hash = (unsigned short*)(ws + 53477376);   // 33,554,432 B
    // hidden hi/lo splits ALIAS out_hash: they are consumed by gemm_v, which
    // completes before attn_kernel (the only writer of out_hash). Stream order
    // serializes qk_split(write) -> gemm_v(read) -> attn(write).
    unsigned short* hH = out_hash;                                 // 16,777,216 B
    unsigned short* hL = out_hash + 8388608;                       // 16,777,216 B
    unsigned short* wH = (unsigned short*)(ws + 87031808);         //  2,097,152 B
    unsigned short* wL = (unsigned short*)(ws + 89128960);         //  2,097,152 B
    unsigned short* qkb = (unsigned short*)(ws + 91226112);        // 16,777,216 B
    float*          ssqo = (float*)(ws + 108003328);               //    524,288 B
    // total 108,527,616 B

    hipLaunchKernelGGL(gemm_qk_split, dim3(9728), dim3(256), 0, stream,
                       hidden, wqk, qk, qkb, ssqo, wv, hH, hL, wH, wL);
    hipLaunchKernelGGL(gemm_v,      dim3(64, 8),   dim3(256), 0, stream,
                       hH, hL, wH, wL, vb);
    hipLaunchKernelGGL(hash_kernel, dim3(2048),    dim3(256), 0, stream,
                       qk, rotf, buckets);
    hipLaunchKernelGGL(sort_kernel, dim3(64),      dim3(256), 0, stream,
                       buckets, sorted);
    hipLaunchKernelGGL(attn_kernel, dim3(128, 16, 2), dim3(256), 0, stream,
                       qkb, ssqo, vb, sorted, out_hash, logits);
    hipLaunchKernelGGL(combine_kernel, dim3(8192), dim3(256), 0, stream,
                       out_hash, logits, out);
}

// Round 15
// 474.008 us; speedup vs baseline: 1.0854x; 1.0790x over previous
//
#include <hip/hip_runtime.h>

// ---------------------------------------------------------------------------
// LSH self-attention (Reformer). B=2,S=4096,H=16,D=64,NH=2,NB=128,CHUNK=64,
// N_BEFORE=1. Inputs fp32, output fp32.
// Precision-critical path (qk projection + hash einsum feeding argmax) is
// fp32 with sequential ascending-k FMA chains (matches np/BLAS order).
// Attention on bf16 MFMA (smooth path).
// gemm_qk history: R4 8x8/128x128 = 224us source ceiling for seq-k fp32.
// R8: split folded into qk dispatch (trailing streamer blocks), 513.3.
// R11/R12: qkb bf16 copy + ssqo sumsq from qk epilogue; attn straight-copy
//   staging. qk<->attn wash (~514); kept for the attn simplification.
// R13: sort split per hash half (bit-identical), 514.5->511.5.
// R14: v projection via SINGLE fp16 MFMA (was bf16x2-split, 3 MFMA terms).
//   fp16 11-bit mantissa -> dot error ~7e-4 rel, ~3x below the bf16
//   output rounding (2^-9) already in the v path. MFMA work /3, staged
//   tiles 4->2, split kernel writes hi only. qk/buckets/P untouched;
//   out = convex comb of v -> delta(out) <= ~3e-3 << absmax 0.0234.
//   Fallback if absmax trips: revert to bf16x2 3-term.
// ---------------------------------------------------------------------------

typedef __attribute__((ext_vector_type(4))) float          f32x4;
typedef __attribute__((ext_vector_type(4))) unsigned short u16x4;
typedef __attribute__((ext_vector_type(8))) unsigned short u16x8;
typedef __attribute__((ext_vector_type(8))) __bf16         bf16x8;
typedef __attribute__((ext_vector_type(8))) _Float16       f16x8;

__device__ __forceinline__ float bf2f(unsigned short u) {
    unsigned int x = ((unsigned int)u) << 16;
    return __builtin_bit_cast(float, x);
}
__device__ __forceinline__ unsigned short f2bf(float f) {
    unsigned int x = __builtin_bit_cast(unsigned int, f);
    x += 0x7FFFu + ((x >> 16) & 1u);
    return (unsigned short)(x >> 16);
}
__device__ __forceinline__ unsigned short f2h(float f) {
    _Float16 h = (_Float16)f;            // v_cvt_f16_f32, RTN
    return __builtin_bit_cast(unsigned short, h);
}

// async global->LDS, 16B per lane, wave-uniform LDS base (HW adds lane*16).
__device__ __forceinline__ void gll16(const unsigned short* g, unsigned short* l) {
    __builtin_amdgcn_global_load_lds(
        (__attribute__((address_space(1))) void*)(g),
        (__attribute__((address_space(3))) void*)(l),
        16, 0, 0);
}

// ---------------------------------------------------------------------------
// Kernel 1a: qk projection (R4-exact core) + hidden/wv fp16 conversion as
// trailing blocks. Blocks 0..511: qk 128x128 tile, 8x8/thread, fp32
// sequential ascending-k FMA — DO NOT change accumulation order (argmax).
// Epilogue emits bf16 qk copy (qkb) + per-row sumsq (ssqo); sumsq scratch
// aliases the dead As/Bs LDS. Blocks 512..9727: fp16 streamer (no LDS).
// ---------------------------------------------------------------------------
__global__ __launch_bounds__(256)
void gemm_qk_split(const float* __restrict__ hidden,
                   const float* __restrict__ wqk,
                   float* __restrict__ qk_out,
                   unsigned short* __restrict__ qkb,
                   float* __restrict__ ssqo,
                   const float* __restrict__ wv,
                   unsigned short* __restrict__ hH16,
                   unsigned short* __restrict__ wH16)
{
    __shared__ __attribute__((aligned(16))) char qsmem[16896];  // As|Bs, later ssq
    float (*As)[132] = (float(*)[132])qsmem;            //  8448 B
    float (*Bs)[132] = (float(*)[132])(qsmem + 8448);   //  8448 B
    const int tid = threadIdx.x;

    if (blockIdx.x >= 512) {
        // ---- fp16 convert: hidden (2097152 vec4) then wv (262144 vec4) ----
        const int idx = (blockIdx.x - 512) * 256 + tid;    // < 2359296
        const bool isw = idx >= 2097152;
        const float* src = isw ? wv : hidden;
        unsigned short* dh = isw ? wH16 : hH16;
        const int v = isw ? (idx - 2097152) : idx;
        const f32x4 x = *((const f32x4*)src + v);
        u16x4 h;
#pragma unroll
        for (int j = 0; j < 4; ++j) h[j] = f2h(x[j]);
        *((u16x4*)dh + v) = h;
        return;
    }

    // ---- qk path (R4-exact main loop) ----
    const int bm  = blockIdx.x & 63;    // 0..63
    const int bn  = blockIdx.x >> 6;    // 0..7

    const float* Asrc = hidden + (size_t)bm * 128 * 1024;
    const float* Bsrc = wqk + (size_t)bn * 128 * 1024;

    const int mlo = (tid & 15) * 4;     // A-read base (16B-stride, 2-way free)
    const int nlo = (tid >> 4) * 4;     // B-read base (broadcast groups)

    float acc[8][8];
#pragma unroll
    for (int r = 0; r < 8; ++r)
#pragma unroll
        for (int c = 0; c < 8; ++c) acc[r][c] = 0.f;

    int srow[2], skof[2];
#pragma unroll
    for (int i = 0; i < 2; ++i) {
        const int c = i * 256 + tid;
        srow[i] = c >> 2;
        skof[i] = (c & 3) * 4;
    }

    f32x4 apre[2], bpre[2];
#pragma unroll
    for (int i = 0; i < 2; ++i) {
        apre[i] = *(const f32x4*)(Asrc + (size_t)srow[i] * 1024 + skof[i]);
        bpre[i] = *(const f32x4*)(Bsrc + (size_t)srow[i] * 1024 + skof[i]);
    }

    for (int ks = 0; ks < 64; ++ks) {   // K = 64 tiles * 16, ascending
#pragma unroll
        for (int i = 0; i < 2; ++i)
#pragma unroll
            for (int j = 0; j < 4; ++j) {
                As[skof[i] + j][srow[i]] = apre[i][j];
                Bs[skof[i] + j][srow[i]] = bpre[i][j];
            }
        __syncthreads();
        if (ks < 63) {
            const int k0 = (ks + 1) * 16;
#pragma unroll
            for (int i = 0; i < 2; ++i) {
                apre[i] = *(const f32x4*)(Asrc + (size_t)srow[i] * 1024 + k0 + skof[i]);
                bpre[i] = *(const f32x4*)(Bsrc + (size_t)srow[i] * 1024 + k0 + skof[i]);
            }
        }
#pragma unroll
        for (int k = 0; k < 16; ++k) {
            f32x4 a0 = *(const f32x4*)&As[k][mlo];
            f32x4 a1 = *(const f32x4*)&As[k][64 + mlo];
            f32x4 b0 = *(const f32x4*)&Bs[k][nlo];
            f32x4 b1 = *(const f32x4*)&Bs[k][64 + nlo];
#pragma unroll
            for (int c = 0; c < 4; ++c) {
#pragma unroll
                for (int r = 0; r < 4; ++r) {
                    acc[r][c]         = __builtin_fmaf(a0[r], b0[c], acc[r][c]);
                    acc[r][c + 4]     = __builtin_fmaf(a0[r], b1[c], acc[r][c + 4]);
                    acc[r + 4][c]     = __builtin_fmaf(a1[r], b0[c], acc[r + 4][c]);
                    acc[r + 4][c + 4] = __builtin_fmaf(a1[r], b1[c], acc[r + 4][c + 4]);
                }
            }
        }
        __syncthreads();
    }

    // ---- epilogue. As/Bs dead past the final barrier: reuse as ssq ----
    float* ssq = (float*)qsmem;          // [16][256] partials, 16384 B

#pragma unroll
    for (int r = 0; r < 8; ++r) {
        const int mm = (r < 4) ? (mlo + r) : (64 + mlo + (r - 4));
#pragma unroll
        for (int g = 0; g < 2; ++g) {
            float p = acc[r][g * 4 + 0] * acc[r][g * 4 + 0];
            p = __builtin_fmaf(acc[r][g * 4 + 1], acc[r][g * 4 + 1], p);
            p = __builtin_fmaf(acc[r][g * 4 + 2], acc[r][g * 4 + 2], p);
            p = __builtin_fmaf(acc[r][g * 4 + 3], acc[r][g * 4 + 3], p);
            ssq[(tid >> 4) * 256 + mm * 2 + g] = p;
        }
    }

#pragma unroll
    for (int r = 0; r < 8; ++r) {
        const int mm = (r < 4) ? (mlo + r) : (64 + mlo + (r - 4));
        const int m  = bm * 128 + mm;
        const int bb = m >> 12, s = m & 4095;
#pragma unroll
        for (int g = 0; g < 2; ++g) {
            const int n  = bn * 128 + (g ? (64 + nlo) : nlo);   // 4-aligned
            const int hh = n >> 6, d = n & 63;
            f32x4 v;
            u16x4 hb;
#pragma unroll
            for (int c = 0; c < 4; ++c) { v[c] = acc[r][g * 4 + c]; hb[c] = f2bf(v[c]); }
            const size_t ob = (((size_t)(bb * 16 + hh)) * 4096 + s) * 64 + d;
            *(f32x4*)&qk_out[ob] = v;
            *(u16x4*)&qkb[ob]    = hb;
        }
    }

    __syncthreads();
    {
        // 256 threads: one (row, g) each. Reads conflict-free (consecutive).
        const int rw = tid >> 1, g = tid & 1;
        float tot = 0.f;
#pragma unroll
        for (int i = 0; i < 16; ++i) tot += ssq[i * 256 + tid];
        const int m  = bm * 128 + rw;
        const int bb = m >> 12, s = m & 4095;
        const int hh = bn * 2 + g;
        ssqo[((size_t)(bb * 16 + hh)) * 4096 + s] = tot;
    }
}

// ---------------------------------------------------------------------------
// Kernel 1b: v projection, single-term fp16 MFMA GEMM (fp32 accum).
// C[m][n] = sum_k h16(A)[m][k] * h16(B)[n][k]; error ~7e-4 rel, below the
// bf16 output rounding. BM=128, BN=128, BK=32, 4 waves, 64x64/wave.
// Output bf16 [B,H,S,D] (same layout the attn kernel consumes).
// ---------------------------------------------------------------------------
__global__ __launch_bounds__(256)
void gemm_v(const unsigned short* __restrict__ hH16,
            const unsigned short* __restrict__ wH16,
            unsigned short* __restrict__ v_out)
{
    __shared__ __attribute__((aligned(16))) unsigned short Ah[128 * 32];
    __shared__ __attribute__((aligned(16))) unsigned short Bh[128 * 32];

    const int tid  = threadIdx.x;
    const int bm   = blockIdx.x;          // 0..63  (M = 8192)
    const int bn   = blockIdx.y;          // 0..7   (N = 1024)
    const int w    = tid >> 6;
    const int lane = tid & 63;
    const int l16  = lane & 15;
    const int quad = lane >> 4;
    const int m0   = (w >> 1) * 64;
    const int n0   = (w & 1) * 64;

    // staging: tile = [128 rows][32 halves] = 8 chunks of 512 halves.
    // wave w stages chunks {2w, 2w+1} of each of the 2 LDS tiles.
    const int c0 = w * 2;
    const int r0 = c0 * 16 + (lane >> 2);   // tile row for chunk c0
    const int r1 = r0 + 16;                 // tile row for chunk c0+1
    const int kf = (lane & 3) * 8;          // k offset in halves

    const size_t abase = (size_t)bm * 128 * 1024;   // halves
    const size_t bbase = (size_t)bn * 128 * 1024;

    f32x4 acc[4][4];
#pragma unroll
    for (int i = 0; i < 4; ++i)
#pragma unroll
        for (int j = 0; j < 4; ++j) acc[i][j] = f32x4{0.f, 0.f, 0.f, 0.f};

    for (int ks = 0; ks < 32; ++ks) {
        const int kb = ks * 32 + kf;
        gll16(hH16 + abase + (size_t)r0 * 1024 + kb, Ah + (size_t)c0 * 512);
        gll16(hH16 + abase + (size_t)r1 * 1024 + kb, Ah + (size_t)(c0 + 1) * 512);
        gll16(wH16 + bbase + (size_t)r0 * 1024 + kb, Bh + (size_t)c0 * 512);
        gll16(wH16 + bbase + (size_t)r1 * 1024 + kb, Bh + (size_t)(c0 + 1) * 512);
        __syncthreads();   // drains vmcnt (global_load_lds) + barrier

        f16x8 ahf[4], bhf[4];
#pragma unroll
        for (int i = 0; i < 4; ++i)
            ahf[i] = *(const f16x8*)&Ah[(m0 + i * 16 + l16) * 32 + quad * 8];
#pragma unroll
        for (int j = 0; j < 4; ++j)
            bhf[j] = *(const f16x8*)&Bh[(n0 + j * 16 + l16) * 32 + quad * 8];
#pragma unroll
        for (int i = 0; i < 4; ++i)
#pragma unroll
            for (int j = 0; j < 4; ++j)
                acc[i][j] = __builtin_amdgcn_mfma_f32_16x16x32_f16(ahf[i], bhf[j], acc[i][j], 0, 0, 0);
        __syncthreads();   // tile fully consumed before next stage overwrites
    }

    // C/D layout [m89]: col = lane&15 (n index), row = quad*4 + reg (m index)
#pragma unroll
    for (int i = 0; i < 4; ++i) {
#pragma unroll
        for (int r = 0; r < 4; ++r) {
            const int m  = bm * 128 + m0 + i * 16 + quad * 4 + r;
            const int bb = m >> 12, s = m & 4095;
#pragma unroll
            for (int j = 0; j < 4; ++j) {
                const int n  = bn * 128 + n0 + j * 16 + l16;
                const int hh = n >> 6, d = n & 63;
                v_out[(((size_t)(bb * 16 + hh)) * 4096 + s) * 64 + d] = f2bf(acc[i][j][r]);
            }
        }
    }
}

// ---------------------------------------------------------------------------
// Kernel 2: hashing. Sequential ascending-d fp32 FMA; argmax over
// concat(rot,-rot), first-occurrence ties. One wave per row-group.
// Reads fp32 qk (exact — buckets must not change).
// ---------------------------------------------------------------------------
__global__ __launch_bounds__(256)
void hash_kernel(const float* __restrict__ qk,
                 const float* __restrict__ rotf,
                 int* __restrict__ buckets)
{
    __shared__ float rot[8192];       // [d][n*64+r]
    __shared__ float rows[64 * 64];
    const int tid = threadIdx.x;
    for (int i = tid; i < 8192; i += 256) rot[i] = rotf[i];
    const int rbase = blockIdx.x * 64;
    {
        const f32x4* src = (const f32x4*)(qk + (size_t)rbase * 64);
        f32x4* dst = (f32x4*)rows;
#pragma unroll
        for (int i = 0; i < 4; ++i) dst[tid + i * 256] = src[tid + i * 256];
    }
    __syncthreads();
    const int w = tid >> 6, lane = tid & 63;
    for (int rr = 0; rr < 16; ++rr) {
        const int row = w * 16 + rr;
        float a0 = 0.f, a1 = 0.f;
#pragma unroll
        for (int dg = 0; dg < 16; ++dg) {
            f32x4 qb = *(const f32x4*)&rows[row * 64 + dg * 4];
#pragma unroll
            for (int j = 0; j < 4; ++j) {
                const int d = dg * 4 + j;
                a0 = __builtin_fmaf(qb[j], rot[d * 128 + lane],      a0);
                a1 = __builtin_fmaf(qb[j], rot[d * 128 + 64 + lane], a1);
            }
        }
        float v0, v1; int i0, i1;
        if (a0 >= -a0) { v0 = a0;  i0 = lane; } else { v0 = -a0; i0 = 64 + lane; }
        if (a1 >= -a1) { v1 = a1;  i1 = lane; } else { v1 = -a1; i1 = 64 + lane; }
#pragma unroll
        for (int m = 1; m < 64; m <<= 1) {
            float ov = __shfl_xor(v0, m); int oi = __shfl_xor(i0, m);
            if (ov > v0 || (ov == v0 && oi < i0)) { v0 = ov; i0 = oi; }
            ov = __shfl_xor(v1, m); oi = __shfl_xor(i1, m);
            if (ov > v1 || (ov == v1 && oi < i1)) { v1 = ov; i1 = oi; }
        }
        if (lane == 0) {
            const int g = rbase + row;
            const int bh = g >> 12, s = g & 4095;
            buckets[(size_t)bh * 8192 + s]        = i0;          // hash 0
            buckets[(size_t)bh * 8192 + 4096 + s] = i1 + 128;    // hash 1
        }
    }
}

// ---------------------------------------------------------------------------
// Kernel 3: stable counting sort, split per (b,h,hash). 64 blocks.
// Hash0 elems (0..4095, buckets<128) and hash1 (4096..8191, buckets>=128)
// sort independently; concat == original stable sort (bit-identical).
// ---------------------------------------------------------------------------
__global__ __launch_bounds__(256)
void sort_kernel(const int* __restrict__ buckets, int* __restrict__ sorted)
{
    __shared__ unsigned char  lb[4096];
    __shared__ unsigned short sl[4096];
    __shared__ int cnt[256];
    __shared__ int base[256];
    __shared__ unsigned short whist[4][256];
    const int tid  = threadIdx.x;
    const int bh   = blockIdx.x >> 1;
    const int hoff = (blockIdx.x & 1) * 4096;   // hash-half offset
    const int lane = tid & 63;
    const int w    = tid >> 6;

    cnt[tid] = 0;
    for (int i = tid; i < 4096; i += 256)
        lb[i] = (unsigned char)buckets[(size_t)bh * 8192 + hoff + i];
    __syncthreads();
    for (int i = tid; i < 4096; i += 256) atomicAdd(&cnt[lb[i]], 1);
    __syncthreads();

    base[tid] = cnt[tid];
    __syncthreads();
#pragma unroll
    for (int off = 1; off < 256; off <<= 1) {
        int t = (tid >= off) ? base[tid - off] : 0;
        __syncthreads();
        base[tid] += t;
        __syncthreads();
    }
    {
        int ex = base[tid] - cnt[tid];
        __syncthreads();
        base[tid] = ex;
        __syncthreads();
    }

    for (int c = 0; c < 16; ++c) {
        const int i = c * 256 + tid;
        const int b = lb[i];
        whist[0][tid] = 0; whist[1][tid] = 0; whist[2][tid] = 0; whist[3][tid] = 0;
        __syncthreads();
        unsigned long long m = ~0ull;
#pragma unroll
        for (int bit = 0; bit < 8; ++bit) {
            const unsigned long long bb = __ballot((b >> bit) & 1);
            m &= ((b >> bit) & 1) ? bb : ~bb;
        }
        const unsigned long long ltmask = (lane == 63) ? ~0ull >> 1
                                         : ((1ull << lane) - 1);
        const int rank_in_wave = __popcll(m & ltmask);
        if (rank_in_wave == 0)
            whist[w][b] = (unsigned short)__popcll(m);
        __syncthreads();
        int rank = rank_in_wave;
#pragma unroll
        for (int ww = 0; ww < 3; ++ww)
            if (ww < w) rank += whist[ww][b];
        const int pos = base[b] + rank;
        sl[pos] = (unsigned short)i;
        __syncthreads();
        base[tid] += whist[0][tid] + whist[1][tid] + whist[2][tid] + whist[3][tid];
        __syncthreads();
    }

    for (int i = tid; i < 4096; i += 256)
        sorted[(size_t)bh * 8192 + hoff + i] = hoff + (int)sl[i];
}

// ---------------------------------------------------------------------------
// Kernel 4: MFMA fused chunked attention. One block per (b,h,chunk).
// Stages bf16 qk rows from qkb (straight copies) + precomputed sumsq.
// ---------------------------------------------------------------------------
#define KQP 72    // kq pitch (shorts): 144B rows, 16B-aligned, 2-way banks
#define VPP 136   // vvt/Pm pitch (shorts): 272B rows, 16B-aligned, 2-way banks

__global__ __launch_bounds__(256)
void attn_kernel(const unsigned short* __restrict__ qkb,
                 const float* __restrict__ ssqo,
                 const unsigned short* __restrict__ vb,
                 const int* __restrict__ sorted,
                 unsigned short* __restrict__ out_hash,
                 float* __restrict__ logits)
{
    __shared__ unsigned short kq[128 * KQP];   // bf16 qk rows (keys 0-127; queries = rows 64-127)
    __shared__ unsigned short vvt[64 * VPP];   // bf16 v transposed [d][key]
    __shared__ unsigned short Pm[64 * VPP];    // bf16 probs [q][key]
    __shared__ float scl[128];
    __shared__ unsigned short stick[128];
    __shared__ unsigned short qtick_lo[64];    // tk & 4095
    __shared__ unsigned short qtick_hi[64];    // tk >> 12
    __shared__ float lg[64];

    const int tid = threadIdx.x;
    const int c  = blockIdx.x;
    const int bh = blockIdx.z * 16 + blockIdx.y;
    const int pc = (c + 127) & 127;

    if (tid < 128) {
        const int p  = (tid < 64) ? (pc * 64 + tid) : (c * 64 + (tid - 64));
        const int tk = sorted[(size_t)bh * 8192 + p];
        stick[tid] = (unsigned short)(tk & 4095);
        if (tid >= 64) {
            qtick_lo[tid - 64] = (unsigned short)(tk & 4095);
            qtick_hi[tid - 64] = (unsigned short)(tk >> 12);
        }
    }
    __syncthreads();

    // ---- staging: bf16 qk rows -> kq (copies), v rows -> vvt^T; scl ----
    {
        const int r = tid >> 1, half = tid & 1;
        const int srow = stick[r];
        const u16x8* src = (const u16x8*)(qkb + (((size_t)bh * 4096 + srow) << 6) + half * 32);
#pragma unroll
        for (int i = 0; i < 4; ++i)
            *(u16x8*)&kq[r * KQP + half * 32 + i * 8] = src[i];

        const unsigned short* vs = vb + (((size_t)bh * 4096 + srow) << 6) + half * 32;
        unsigned short vtmp[32];
#pragma unroll
        for (int i = 0; i < 4; ++i)
            *(u16x8*)&vtmp[i * 8] = *(const u16x8*)(vs + i * 8);
#pragma unroll
        for (int j = 0; j < 32; ++j)
            vvt[(half * 32 + j) * VPP + r] = vtmp[j];
    }
    if (tid < 128) {
        const float ss = ssqo[(size_t)bh * 4096 + stick[tid]];
        scl[tid] = (1.0f / sqrtf(ss * (1.0f / 64.0f) + 1e-6f)) * 0.125f;
    }
    __syncthreads();

    const int w    = tid >> 6;          // wave -> q-strip [w*16, w*16+16)
    const int lane = tid & 63;
    const int l16  = lane & 15;
    const int quad = lane >> 4;

    // ---- QK^T: 16 MFMA per wave ----
    f32x4 accS[8];
#pragma unroll
    for (int t = 0; t < 8; ++t) accS[t] = f32x4{0.f, 0.f, 0.f, 0.f};
#pragma unroll
    for (int kst = 0; kst < 2; ++kst) {
        const bf16x8 aq = *(const bf16x8*)&kq[(64 + w * 16 + l16) * KQP + kst * 32 + quad * 8];
#pragma unroll
        for (int t = 0; t < 8; ++t) {
            const bf16x8 bk = *(const bf16x8*)&kq[(t * 16 + l16) * KQP + kst * 32 + quad * 8];
            accS[t] = __builtin_amdgcn_mfma_f32_16x16x32_bf16(aq, bk, accS[t], 0, 0, 0);
        }
    }

    // ---- scale + mask + softmax (in-register, 16-lane reduce) ----
    float sct[8]; int tkt[8];
#pragma unroll
    for (int t = 0; t < 8; ++t) {
        sct[t] = scl[t * 16 + l16];
        tkt[t] = (int)stick[t * 16 + l16];
    }
    int tqr[4];
#pragma unroll
    for (int r = 0; r < 4; ++r) tqr[r] = (int)stick[64 + w * 16 + quad * 4 + r];

    float val[8][4];
#pragma unroll
    for (int t = 0; t < 8; ++t)
#pragma unroll
        for (int r = 0; r < 4; ++r) {
            float a = accS[t][r] * sct[t];
            if (tqr[r] <  tkt[t]) a = -1e9f;
            if (tqr[r] == tkt[t]) a = -1e5f;
            val[t][r] = a;
        }

    float inv_r[4], logit_r[4];
#pragma unroll
    for (int r = 0; r < 4; ++r) {
        float m = val[0][r];
#pragma unroll
        for (int t = 1; t < 8; ++t) m = fmaxf(m, val[t][r]);
        m = fmaxf(m, __shfl_xor(m, 1));
        m = fmaxf(m, __shfl_xor(m, 2));
        m = fmaxf(m, __shfl_xor(m, 4));
        m = fmaxf(m, __shfl_xor(m, 8));
        float l = 0.f;
#pragma unroll
        for (int t = 0; t < 8; ++t) { val[t][r] = expf(val[t][r] - m); l += val[t][r]; }
        l += __shfl_xor(l, 1);
        l += __shfl_xor(l, 2);
        l += __shfl_xor(l, 4);
        l += __shfl_xor(l, 8);
        logit_r[r] = m + logf(l);
        inv_r[r]   = 1.0f / l;
    }

    // P (bf16) to LDS in [q][key] layout; logits to LDS
#pragma unroll
    for (int t = 0; t < 8; ++t)
#pragma unroll
        for (int r = 0; r < 4; ++r)
            Pm[(w * 16 + quad * 4 + r) * VPP + t * 16 + l16] = f2bf(val[t][r] * inv_r[r]);
    if (l16 == 0) {
#pragma unroll
        for (int r = 0; r < 4; ++r) lg[w * 16 + quad * 4 + r] = logit_r[r];
    }
    __syncthreads();

    // ---- PV: 16 MFMA per wave ----
    f32x4 accO[4];
#pragma unroll
    for (int dt = 0; dt < 4; ++dt) accO[dt] = f32x4{0.f, 0.f, 0.f, 0.f};
#pragma unroll
    for (int kst = 0; kst < 4; ++kst) {
        const bf16x8 ap = *(const bf16x8*)&Pm[(w * 16 + l16) * VPP + kst * 32 + quad * 8];
#pragma unroll
        for (int dt = 0; dt < 4; ++dt) {
            const bf16x8 bv = *(const bf16x8*)&vvt[(dt * 16 + l16) * VPP + kst * 32 + quad * 8];
            accO[dt] = __builtin_amdgcn_mfma_f32_16x16x32_bf16(ap, bv, accO[dt], 0, 0, 0);
        }
    }

    // ---- output: bf16 via LDS (reuse kq as outb [64][KQP]) ----
    unsigned short* outb = kq;   // all kq reads completed before Pm barrier
#pragma unroll
    for (int dt = 0; dt < 4; ++dt)
#pragma unroll
        for (int r = 0; r < 4; ++r)
            outb[(w * 16 + quad * 4 + r) * KQP + dt * 16 + l16] = f2bf(accO[dt][r]);
    __syncthreads();

    if (tid < 64) {
        const int n = qtick_hi[tid], s = qtick_lo[tid];
        logits[((size_t)bh * 2 + n) * 4096 + s] = lg[tid];
    }
    {
        const int qq = tid >> 2, part = tid & 3;
        const int n = qtick_hi[qq], s = qtick_lo[qq];
        const size_t ob = (((size_t)bh * 2 + n) * 4096 + s) * 64 + part * 16;
        u16x8 u0 = *(const u16x8*)&outb[qq * KQP + part * 16];
        u16x8 u1 = *(const u16x8*)&outb[qq * KQP + part * 16 + 8];
        *(u16x8*)(out_hash + ob)     = u0;
        *(u16x8*)(out_hash + ob + 8) = u1;
    }
}

// ---------------------------------------------------------------------------
// Kernel 5: combine hash rounds with logsumexp weights; emit fp32 [B,S,H*D].
// ---------------------------------------------------------------------------
__global__ __launch_bounds__(256)
void combine_kernel(const unsigned short* __restrict__ out_hash,
                    const float* __restrict__ logits,
                    float* __restrict__ out)
{
    const int idx  = blockIdx.x * 256 + threadIdx.x;   // < 2097152
    const int bh   = idx >> 16;
    const int rem  = idx & 65535;
    const int s    = rem >> 4;
    const int part = rem & 15;
    const float lg0 = logits[((size_t)bh * 2 + 0) * 4096 + s];
    const float lg1 = logits[((size_t)bh * 2 + 1) * 4096 + s];
    const float m  = fmaxf(lg0, lg1);
    const float e0 = expf(lg0 - m), e1 = expf(lg1 - m);
    const float inv = 1.0f / (e0 + e1);
    const float w0 = e0 * inv, w1 = e1 * inv;
    const size_t b0 = (((size_t)bh * 2 + 0) * 4096 + s) * 64 + part * 4;
    const size_t b1 = (((size_t)bh * 2 + 1) * 4096 + s) * 64 + part * 4;
    u16x4 u0 = *(const u16x4*)(out_hash + b0);
    u16x4 u1 = *(const u16x4*)(out_hash + b1);
    const int b = bh >> 4, hh = bh & 15;
    const size_t ob = ((size_t)b * 4096 + s) * 1024 + hh * 64 + part * 4;
    f32x4 r;
#pragma unroll
    for (int e = 0; e < 4; ++e)
        r[e] = w0 * bf2f(u0[e]) + w1 * bf2f(u1[e]);
    *(f32x4*)(out + ob) = r;
}

// ---------------------------------------------------------------------------
extern "C" void kernel_launch(void* const* d_in, const int* in_sizes, int n_in,
                              void* d_out, int out_size, void* d_ws, size_t ws_size,
                              hipStream_t stream) {
    const float* hidden = (const float*)d_in[0];   // [2,4096,1024] fp32
    const float* wqk    = (const float*)d_in[1];   // [1024,1024]   fp32
    const float* wv     = (const float*)d_in[2];   // [1024,1024]   fp32
    const float* rotf   = (const float*)d_in[3];   // [64,2,64]     fp32
    float* out = (float*)d_out;                    // [2,4096,1024] fp32

    char* ws = (char*)d_ws;
    float*          qk       = (float*)(ws);                       // 33,554,432 B
    unsigned short* vb       = (unsigned short*)(ws + 33554432);   // 16,777,216 B
    int*            buckets  = (int*)(ws + 50331648);              //  1,048,576 B
    int*            sorted   = (int*)(ws + 51380224);              //  1,048,576 B
    float*          logits   = (float*)(ws + 52428800);            //  1,048,576 B
    unsigned short* out_hash = (unsigned short*)(ws + 53477376);   // 33,554,432 B
    // hidden fp16 ALIASES out_hash: consumed by gemm_v, which completes
    // before attn_kernel (the only writer of out_hash). Stream order
    // serializes qk_split(write) -> gemm_v(read) -> attn(write).
    unsigned short* hH16 = out_hash;                               // 16,777,216 B
    unsigned short* wH16 = (unsigned short*)(ws + 87031808);       //  2,097,152 B
    unsigned short* qkb  = (unsigned short*)(ws + 89128960);       // 16,777,216 B
    float*          ssqo = (float*)(ws + 105906176);               //    524,288 B
    // total 106,430,464 B

    hipLaunchKernelGGL(gemm_qk_split, dim3(9728), dim3(256), 0, stream,
                       hidden, wqk, qk, qkb, ssqo, wv, hH16, wH16);
    hipLaunchKernelGGL(gemm_v,      dim3(64, 8),   dim3(256), 0, stream,
                       hH16, wH16, vb);
    hipLaunchKernelGGL(hash_kernel, dim3(2048),    dim3(256), 0, stream,
                       qk, rotf, buckets);
    hipLaunchKernelGGL(sort_kernel, dim3(64),      dim3(256), 0, stream,
                       buckets, sorted);
    hipLaunchKernelGGL(attn_kernel, dim3(128, 16, 2), dim3(256), 0, stream,
                       qkb, ssqo, vb, sorted, out_hash, logits);
    hipLaunchKernelGGL(combine_kernel, dim3(8192), dim3(256), 0, stream,
                       out_hash, logits, out);
}